// Round 9
// baseline (129.664 us; speedup 1.0000x reference)
//
#include <hip/hip_runtime.h>
#include <hip/hip_bf16.h>
#include <cstdint>
#include <math.h>

// Shapes: B=256, P=128, K=512, HE=1024, HF=512 (2HF=1024), D=2560, HID=64
// Outputs: embeddings (256,1,1536) then weights (256,128), fp32, flat-concat.
//
// R8: 512-thread attn block (8 waves = 2/SIMD; R7 counters showed 1 wave/SIMD
// exposed every phase latency: MfmaUtil 2.6%, VALUBusy 5.2%, occ 9.6%).
// qf staged to LDS so proj-MFMA phase P is LDS(A) + L2(B) only; GEMM A-frags
// preloaded to registers (1 M-tile/wave).
// Ledger (attn µs): R2 39 | R3 44 | R5 95 | R6 65 | R7 42 (w/ proj folded in).
// Lessons: no inter-block coupling; vmcnt is one per-wave queue (phases stay
// dependency-homogeneous; syncs drain it); pipelines = explicit reg arrays.

typedef __bf16 bf16;
typedef __attribute__((ext_vector_type(8))) __bf16 bf16x8;
typedef __attribute__((ext_vector_type(4))) __bf16 bf16x4;
typedef __attribute__((ext_vector_type(4))) float f32x4;

#define NB 256
#define NP 128
#define NK 512
#define SKLD 520   // keys LDS row stride (bf16): 1040B/row -> 2-way bank alias (free)
#define SK_BYTES (NP * SKLD * 2)                  // 133120
#define SQF_OFF  SK_BYTES                         // qf bf16[2048]       (4096B)
#define SCORES_OFF (SQF_OFF + 4096)               // scores f32[128]
#define WTS_OFF    (SCORES_OFF + 512)             // wts f32[128]
#define PP_OFF     (WTS_OFF + 512)                // pp f32[8][64]       (2048B)
#define W2_OFF     (PP_OFF + 2048)                // w2l f32[64]
#define CP_OFF     (W2_OFF + 256)                 // cpart f32[512]      (2048B)
#define SMEM_BYTES (CP_OFF + 2048)                // 142592 < 160K

// ---------------- prep: weight repack only ----------------
// blocks 0..15 : w1kt[h][k]  = bf16(W1[k*64+h]),        k-rows [32j,32j+32)
// blocks 16..79: w1qft[h][d] = bf16(W1[(512+d)*64+h]),  d-rows [32j,32j+32)
__global__ __launch_bounds__(256) void prep_kernel(
    const float* __restrict__ W1, bf16* __restrict__ w1kt,
    bf16* __restrict__ w1qft)
{
    const int blk = blockIdx.x;
    const int t = threadIdx.x;
    __shared__ float s[32][65];
    if (blk < 16) {
        const int k0 = blk * 32;
#pragma unroll
        for (int i = 0; i < 8; i++) {
            const int idx = t + 256 * i;
            const int k = idx >> 6, h = idx & 63;
            s[k][h] = W1[(size_t)(k0 + k) * 64 + h];
        }
        __syncthreads();
#pragma unroll
        for (int i = 0; i < 8; i++) {
            const int idx = t + 256 * i;
            const int h = idx >> 5, kk = idx & 31;
            w1kt[(size_t)h * 512 + k0 + kk] = (bf16)s[kk][h];
        }
    } else {
        const int j = blk - 16;              // 0..63
        const int d0 = j * 32;
#pragma unroll
        for (int i = 0; i < 8; i++) {
            const int idx = t + 256 * i;
            const int r = idx >> 6, h = idx & 63;
            s[r][h] = W1[(size_t)(512 + d0 + r) * 64 + h];
        }
        __syncthreads();
#pragma unroll
        for (int i = 0; i < 8; i++) {
            const int idx = t + 256 * i;
            const int h = idx >> 5, rr = idx & 31;
            w1qft[(size_t)h * 2048 + d0 + rr] = (bf16)s[rr][h];
        }
    }
}

// ---------------- attn: fused, one block per batch, 8 waves ----------------
__global__ __launch_bounds__(512, 2) void attn_kernel(
    const float* __restrict__ keys, const float* __restrict__ query,
    const float* __restrict__ frame, const int* __restrict__ mask,
    const float* __restrict__ W2, const bf16* __restrict__ w1kt,
    const bf16* __restrict__ w1qft, float* __restrict__ out)
{
    extern __shared__ char smem[];
    bf16* sk      = (bf16*)smem;                   // [128][520] bf16
    bf16* sqf     = (bf16*)(smem + SQF_OFF);       // [2048] concat(query,frame) bf16
    float* scores = (float*)(smem + SCORES_OFF);   // [128]
    float* wts    = (float*)(smem + WTS_OFF);      // [128]
    float* pp     = (float*)(smem + PP_OFF);       // [8][64] proj partials
    float* w2l    = (float*)(smem + W2_OFF);       // [64]
    float* cpart  = (float*)(smem + CP_OFF);       // [512] context partials

    const int b = blockIdx.x;
    const int t = threadIdx.x;
    const int w = t >> 6;          // wave 0..7
    const int lane = t & 63;
    const int m = lane & 15;
    const int q = lane >> 4;

    if (t < 64) w2l[t] = W2[t];

    // ---- phase A: stage qf (4KB) + keys[b] (256KB fp32) -> LDS bf16 ----
    {
        // qf: threads 0..255 query, 256..511 frame (1 float4 each)
        const float* qsrc = (t < 256 ? query : frame) + (size_t)b * 1024 + (t & 255) * 4;
        const float4 qv = *(const float4*)qsrc;

        const int rowadd = t >> 7;            // 0..3
        const int c0 = (t & 127) * 4;
        const float* kb = keys + (size_t)b * (NP * NK);
        float4 kv[2][8];
#pragma unroll
        for (int ii = 0; ii < 8; ii++)
            kv[0][ii] = *(const float4*)(kb + (size_t)(4 * ii + rowadd) * 512 + (t & 127) * 4);

        bf16x4 qb;
        qb[0] = (bf16)qv.x; qb[1] = (bf16)qv.y; qb[2] = (bf16)qv.z; qb[3] = (bf16)qv.w;
        *(bf16x4*)(sqf + t * 4) = qb;

#pragma unroll
        for (int g = 0; g < 4; g++) {
            const int cur = g & 1;
            if (g < 3) {
#pragma unroll
                for (int ii = 0; ii < 8; ii++)
                    kv[cur ^ 1][ii] = *(const float4*)(
                        kb + (size_t)(4 * ((g + 1) * 8 + ii) + rowadd) * 512 + (t & 127) * 4);
            }
#pragma unroll
            for (int ii = 0; ii < 8; ii++) {
                const float4 v = kv[cur][ii];
                bf16x4 bv;
                bv[0] = (bf16)v.x; bv[1] = (bf16)v.y;
                bv[2] = (bf16)v.z; bv[3] = (bf16)v.w;
                *(bf16x4*)(sk + (size_t)(4 * (g * 8 + ii) + rowadd) * SKLD + c0) = bv;
            }
        }
    }
    __syncthreads();

    // ---- phase P: proj partial for d-chunk [256w, 256w+256) via MFMA ----
    // A = qf broadcast rows from LDS (conflict-free broadcast); B = w1qft (L2).
    {
        const bf16* wb = w1qft + (size_t)m * 2048 + w * 256 + q * 8;  // +nt*32768 +kk*32
        f32x4 pacc[4];
#pragma unroll
        for (int nt = 0; nt < 4; nt++) pacc[nt] = (f32x4){0.f, 0.f, 0.f, 0.f};

        bf16x8 Bp[4];
#pragma unroll
        for (int nt = 0; nt < 4; nt++) Bp[nt] = *(const bf16x8*)(wb + nt * 32768);

#pragma unroll
        for (int kk = 0; kk < 8; kk++) {
            const bf16x8 Af = *(const bf16x8*)(sqf + w * 256 + kk * 32 + q * 8);
            bf16x8 Bc[4];
#pragma unroll
            for (int nt = 0; nt < 4; nt++) Bc[nt] = Bp[nt];
            if (kk < 7) {
#pragma unroll
                for (int nt = 0; nt < 4; nt++)
                    Bp[nt] = *(const bf16x8*)(wb + nt * 32768 + (kk + 1) * 32);
            }
#pragma unroll
            for (int nt = 0; nt < 4; nt++)
                pacc[nt] = __builtin_amdgcn_mfma_f32_16x16x32_bf16(Af, Bc[nt], pacc[nt], 0, 0, 0);
        }
        if (q == 0) {
#pragma unroll
            for (int nt = 0; nt < 4; nt++)
                pp[w * 64 + nt * 16 + m] = pacc[nt][0];
        }
    }
    __syncthreads();

    // ---- phase G: wave w owns M-tile rows [16w,16w+16); A preloaded to regs ----
    const int pw = w * 16;
    bf16x8 Av[16];
#pragma unroll
    for (int kk = 0; kk < 16; kk++)
        Av[kk] = *(const bf16x8*)(sk + (pw + m) * SKLD + kk * 32 + q * 8);

    const bf16* bbase = w1kt + (size_t)m * 512 + q * 8;   // + nt*16*512 + kk*32
    bf16x8 Bv[2][16];
#pragma unroll
    for (int kk = 0; kk < 16; kk++)
        Bv[0][kk] = *(const bf16x8*)(bbase + kk * 32);

    float pr[4] = {0.f, 0.f, 0.f, 0.f};
#pragma unroll
    for (int nt = 0; nt < 4; nt++) {
        const int cur = nt & 1;
        if (nt < 3) {
#pragma unroll
            for (int kk = 0; kk < 16; kk++)
                Bv[cur ^ 1][kk] = *(const bf16x8*)(bbase + (nt + 1) * 8192 + kk * 32);
        }
        f32x4 acc = (f32x4){0.f, 0.f, 0.f, 0.f};
#pragma unroll
        for (int kk = 0; kk < 16; kk++)
            acc = __builtin_amdgcn_mfma_f32_16x16x32_bf16(Av[kk], Bv[cur][kk], acc, 0, 0, 0);
        // fold this nt's 16 h-columns into running score partials
        const int h = nt * 16 + m;
        const float pv = pp[h] + pp[64 + h] + pp[128 + h] + pp[192 + h]
                       + pp[256 + h] + pp[320 + h] + pp[384 + h] + pp[448 + h];
        const float wv = w2l[h];
#pragma unroll
        for (int r = 0; r < 4; r++)
            pr[r] += fmaxf(acc[r] + pv, 0.f) * wv;
    }

    // ---- reduce over the 16 h-lanes, write scores[p] ----
#pragma unroll
    for (int off = 1; off < 16; off <<= 1) {
#pragma unroll
        for (int r = 0; r < 4; r++) pr[r] += __shfl_xor(pr[r], off);
    }
    if (m == 0) {
        const int pbase = pw + q * 4;
#pragma unroll
        for (int r = 0; r < 4; r++) scores[pbase + r] = pr[r];
    }
    __syncthreads();

    // ---- masked softmax over 128 scores (wave 0), write weights ----
    if (w == 0) {
        const int pa = lane, pb = lane + 64;
        float s0 = (mask[b * 128 + pa] == 0) ? -INFINITY : scores[pa];
        float s1 = (mask[b * 128 + pb] == 0) ? -INFINITY : scores[pb];
        float mx = fmaxf(s0, s1);
#pragma unroll
        for (int off = 32; off; off >>= 1) mx = fmaxf(mx, __shfl_xor(mx, off));
        float e0 = __expf(s0 - mx), e1 = __expf(s1 - mx);
        float sum = e0 + e1;
#pragma unroll
        for (int off = 32; off; off >>= 1) sum += __shfl_xor(sum, off);
        const float inv = 1.0f / sum;
        e0 *= inv; e1 *= inv;
        wts[pa] = e0; wts[pb] = e1;
        float* wout = out + (size_t)NB * 1536;
        wout[b * 128 + pa] = e0;
        wout[b * 128 + pb] = e1;
    }
    __syncthreads();

    // ---- context: thread (tg=t>>8, tc=t&255) does cols 2tc,2tc+1 over 64 rows ----
    {
        const int tg = t >> 8;
        const int tc = t & 255;
        float a0 = 0.f, a1 = 0.f;
#pragma unroll 8
        for (int i = 0; i < 64; i++) {
            const int p = tg * 64 + i;
            const float wv = wts[p];
            const uint32_t uv = *(const uint32_t*)(sk + (size_t)p * SKLD + 2 * tc);
            a0 += wv * __uint_as_float(uv << 16);
            a1 += wv * __uint_as_float(uv & 0xffff0000u);
        }
        if (tg == 1) {
            cpart[2 * tc] = a0;
            cpart[2 * tc + 1] = a1;
        }
        __syncthreads();
        if (tg == 0) {
            out[(size_t)b * 1536 + 2 * tc]     = a0 + cpart[2 * tc];
            out[(size_t)b * 1536 + 2 * tc + 1] = a1 + cpart[2 * tc + 1];
        }
    }
    // ---- frame passthrough: embeddings[:, 512:1536] = frameLSTM_h ----
    {
        const float2 fv = *(const float2*)(frame + (size_t)b * 1024 + t * 2);
        *(float2*)(out + (size_t)b * 1536 + 512 + t * 2) = fv;
    }
}

extern "C" void kernel_launch(void* const* d_in, const int* in_sizes, int n_in,
                              void* d_out, int out_size, void* d_ws, size_t ws_size,
                              hipStream_t stream) {
    const float* query = (const float*)d_in[0];
    const float* keys  = (const float*)d_in[1];
    const float* frame = (const float*)d_in[2];
    const int*   mask  = (const int*)d_in[3];
    const float* W1    = (const float*)d_in[4];
    const float* W2    = (const float*)d_in[5];
    float* out = (float*)d_out;

    // ws: [0,64K) w1kt bf16 [64][512]; [64K,320K) w1qft bf16 [64][2048]
    bf16* w1kt  = (bf16*)d_ws;
    bf16* w1qft = (bf16*)((char*)d_ws + (64 << 10));

    hipFuncSetAttribute((const void*)attn_kernel,
                        hipFuncAttributeMaxDynamicSharedMemorySize, SMEM_BYTES);

    prep_kernel<<<80, 256, 0, stream>>>(W1, w1kt, w1qft);
    attn_kernel<<<256, 512, SMEM_BYTES, stream>>>(keys, query, frame, mask, W2,
                                                  w1kt, w1qft, out);
}